// Round 17
// baseline (111.571 us; speedup 1.0000x reference)
//
#include <hip/hip_runtime.h>

#define BB 4
#define CC 256
#define CQ 32
#define NN 4096   // 64*64

typedef __attribute__((ext_vector_type(8))) short bf16x8;
typedef __attribute__((ext_vector_type(16))) float f32x16;

__device__ __forceinline__ unsigned short f2bf(float f) {
    unsigned int u = __float_as_uint(f);
    unsigned int r = (u + 0x7fffu + ((u >> 16) & 1u)) >> 16;
    return (unsigned short)r;
}

// drain-free barrier: order LDS ops across waves WITHOUT waiting on
// outstanding global stores (vmcnt untouched -> store pipeline keeps flowing)
__device__ __forceinline__ void lds_barrier() {
    asm volatile("s_waitcnt lgkmcnt(0)\n\ts_barrier" ::: "memory");
}

// ---------------------------------------------------------------------------
// K1: Q/K projections -> transposed bf16 buffers [b][n][cq].  (R16-identical)
// ---------------------------------------------------------------------------
__global__ __launch_bounds__(128) void qk_proj_kernel(
    const float* __restrict__ x,
    const float* __restrict__ wq, const float* __restrict__ bq,
    const float* __restrict__ wk, const float* __restrict__ bk,
    unsigned short* __restrict__ Qtb, unsigned short* __restrict__ Ktb,
    float* __restrict__ out)
{
    const int n   = blockIdx.x * 128 + threadIdx.x;
    const int grp = blockIdx.y;
    const int b   = blockIdx.z;
    const bool isQ = (grp < 4);
    const bool doCopy = (grp == 0);
    const int o0 = (grp & 3) * 8;

    const float* w    = isQ ? wq : wk;
    const float* bias = isQ ? bq : bk;

    float acc[8];
    #pragma unroll
    for (int u = 0; u < 8; ++u) acc[u] = bias[o0 + u];

    const float* xp = x + (size_t)b * CC * NN + n;
    float* op = out + (size_t)b * CC * NN + n;
    const float* wp = w + (size_t)o0 * CC;
    #pragma unroll 8
    for (int c = 0; c < CC; ++c) {
        float xv = xp[(size_t)c * NN];
        if (doCopy) op[(size_t)c * NN] = xv;
        #pragma unroll
        for (int u = 0; u < 8; ++u) acc[u] += wp[u * CC + c] * xv;
    }

    unsigned int pk[4];
    #pragma unroll
    for (int j = 0; j < 4; ++j)
        pk[j] = (unsigned int)f2bf(acc[2 * j]) | ((unsigned int)f2bf(acc[2 * j + 1]) << 16);

    unsigned short* dst = (isQ ? Qtb : Ktb) + ((size_t)b * NN + n) * CQ;
    *reinterpret_cast<uint4*>(dst + o0) = make_uint4(pk[0], pk[1], pk[2], pk[3]);
}

// ---------------------------------------------------------------------------
// K2: V projection (gamma-guarded; grid-stride)
// ---------------------------------------------------------------------------
__global__ __launch_bounds__(256) void v_proj_kernel(
    const float* __restrict__ x,
    const float* __restrict__ wv, const float* __restrict__ bv,
    const float* __restrict__ gamma,
    float* __restrict__ Vt)
{
    if (gamma[0] == 0.f) return;
    for (int task = blockIdx.x; task < 2048; task += 256) {
        const int n  = (task & 15) * 256 + threadIdx.x;
        const int c0 = ((task >> 4) & 31) * 8;
        const int b  = task >> 9;

        float acc[8];
        #pragma unroll
        for (int u = 0; u < 8; ++u) acc[u] = 0.f;

        const float* xp = x + (size_t)b * CC * NN + n;
        #pragma unroll 4
        for (int c = 0; c < CC; ++c) {
            float xv = xp[(size_t)c * NN];
            #pragma unroll
            for (int u = 0; u < 8; ++u) acc[u] += wv[(size_t)(c0 + u) * CC + c] * xv;
        }
        #pragma unroll
        for (int u = 0; u < 8; ++u)
            Vt[((size_t)b * NN + n) * CC + c0 + u] = acc[u] + bv[c0 + u];
    }
}

// ---------------------------------------------------------------------------
// K3: 2-pass MFMA energy + softmax. Pass 1 + XCD swizzle: R16-identical.
// Pass 2 REWRITTEN: 8 macro-steps of 512 cols; all waves stage exp() into
// shared sbuf[32][517] (stage writes 2-way/free; store reads data-rate);
// then each wave stores 4 rows x 2KB FULLY CONTIGUOUS (2 adjacent float4
// instrs/row), rows chaining sequentially across macros. Barriers are raw
// "lgkmcnt(0); s_barrier" — LDS-ordered but NO vmcnt drain: global stores
// pipeline across all macros (the thing __syncthreads forbids).
// Stage math identical to R16 -> absmax must stay 6.103516e-05 exactly.
// ---------------------------------------------------------------------------
__global__ __launch_bounds__(512, 4) void attn_kernel(
    const unsigned short* __restrict__ Qtb,
    const unsigned short* __restrict__ Ktb,
    float* __restrict__ att)
{
    __shared__ float red_s[8][32];
    __shared__ float rowls[32];
    __shared__ __align__(16) float sbuf[32][517];

    const int tid  = threadIdx.x;
    const int w    = tid >> 6;
    const int lane = tid & 63;
    const int l31  = lane & 31;
    const int h    = lane >> 5;

    // XCD-aware bijective swizzle (R16): XCD (flat&7) -> contiguous 64 tiles
    const int flat = blockIdx.x;
    const int orig = (flat >> 3) + ((flat & 7) << 6);
    const int b    = orig >> 7;
    const int i0   = (orig & 127) * 32;

    // Q-frags (B operand): col i = i0+l31; k-chunks h and h+2 (8 cq each)
    const unsigned short* qb = Qtb + ((size_t)b * NN + i0 + l31) * CQ;
    const bf16x8 a0 = *reinterpret_cast<const bf16x8*>(qb + h * 8);
    const bf16x8 a1 = *reinterpret_cast<const bf16x8*>(qb + (h + 2) * 8);

    // ---------------- pass 1: per-lane row-sum of exp (R16-identical) ------
    const unsigned short* kf = Ktb + ((size_t)b * NN + w * 512 + l31) * CQ;
    float s = 0.f;
    {
        bf16x8 nb0 = *reinterpret_cast<const bf16x8*>(kf + h * 8);
        bf16x8 nb1 = *reinterpret_cast<const bf16x8*>(kf + (h + 2) * 8);
        #pragma unroll
        for (int u = 0; u < 16; ++u) {
            bf16x8 b0 = nb0, b1 = nb1;
            if (u < 15) {
                const unsigned short* kp = kf + (size_t)(u + 1) * 32 * CQ;
                nb0 = *reinterpret_cast<const bf16x8*>(kp + h * 8);
                nb1 = *reinterpret_cast<const bf16x8*>(kp + (h + 2) * 8);
            }
            f32x16 acc{};
            acc = __builtin_amdgcn_mfma_f32_32x32x16_bf16(b0, a0, acc, 0, 0, 0);
            acc = __builtin_amdgcn_mfma_f32_32x32x16_bf16(b1, a1, acc, 0, 0, 0);
            float p0 = 0.f, p1 = 0.f;
            #pragma unroll
            for (int q = 0; q < 16; q += 2) {
                p0 += __expf(acc[q]);
                p1 += __expf(acc[q + 1]);
            }
            s += p0 + p1;
        }
    }
    s += __shfl_xor(s, 32, 64);
    if (h == 0) red_s[w][l31] = s;
    __syncthreads();
    if (tid < 32) {
        float t = red_s[0][tid];
        #pragma unroll
        for (int ww = 1; ww < 8; ++ww) t += red_s[ww][tid];
        rowls[tid] = -__logf(t);
    }
    __syncthreads();
    const float lis = rowls[l31];

    // ------- pass 2: 512-col macros, shared stage, 2KB/row drain-free ------
    // wave w computes cols m*512 + w*64 + s*32 + kc  (s=0,1)
    const unsigned short* kfw = Ktb + ((size_t)b * NN + w * 64 + l31) * CQ;
    float* arow = att + ((size_t)b * NN + i0) * NN;

    // preload macro-0 frags (s=0 and s=1)
    bf16x8 c00 = *reinterpret_cast<const bf16x8*>(kfw + h * 8);
    bf16x8 c01 = *reinterpret_cast<const bf16x8*>(kfw + (h + 2) * 8);
    bf16x8 c10 = *reinterpret_cast<const bf16x8*>(kfw + (size_t)32 * CQ + h * 8);
    bf16x8 c11 = *reinterpret_cast<const bf16x8*>(kfw + (size_t)32 * CQ + (h + 2) * 8);

    #pragma unroll
    for (int m = 0; m < 8; ++m) {
        // ---- stage: 2 sub-tiles of 32 cols into sbuf ----
        {
            f32x16 acc{};
            acc = __builtin_amdgcn_mfma_f32_32x32x16_bf16(c00, a0, acc, 0, 0, 0);
            acc = __builtin_amdgcn_mfma_f32_32x32x16_bf16(c01, a1, acc, 0, 0, 0);
            #pragma unroll
            for (int g2 = 0; g2 < 4; ++g2) {
                float4 e4;
                e4.x = __expf(acc[4 * g2 + 0] + lis);
                e4.y = __expf(acc[4 * g2 + 1] + lis);
                e4.z = __expf(acc[4 * g2 + 2] + lis);
                e4.w = __expf(acc[4 * g2 + 3] + lis);
                *reinterpret_cast<float4*>(&sbuf[l31][w * 64 + 8 * g2 + 4 * h]) = e4;
            }
        }
        {
            f32x16 acc{};
            acc = __builtin_amdgcn_mfma_f32_32x32x16_bf16(c10, a0, acc, 0, 0, 0);
            acc = __builtin_amdgcn_mfma_f32_32x32x16_bf16(c11, a1, acc, 0, 0, 0);
            #pragma unroll
            for (int g2 = 0; g2 < 4; ++g2) {
                float4 e4;
                e4.x = __expf(acc[4 * g2 + 0] + lis);
                e4.y = __expf(acc[4 * g2 + 1] + lis);
                e4.z = __expf(acc[4 * g2 + 2] + lis);
                e4.w = __expf(acc[4 * g2 + 3] + lis);
                *reinterpret_cast<float4*>(&sbuf[l31][w * 64 + 32 + 8 * g2 + 4 * h]) = e4;
            }
        }
        // prefetch next macro's frags (latency hides under store phase)
        if (m < 7) {
            const unsigned short* kp = kfw + (size_t)(m + 1) * 512 * CQ;
            c00 = *reinterpret_cast<const bf16x8*>(kp + h * 8);
            c01 = *reinterpret_cast<const bf16x8*>(kp + (h + 2) * 8);
            c10 = *reinterpret_cast<const bf16x8*>(kp + (size_t)32 * CQ + h * 8);
            c11 = *reinterpret_cast<const bf16x8*>(kp + (size_t)32 * CQ + (h + 2) * 8);
        }
        lds_barrier();   // LDS visible; stores NOT drained

        // ---- store: wave w -> rows {w, 8+w, 16+w, 24+w}, 2KB contiguous ---
        #pragma unroll
        for (int i = 0; i < 4; ++i) {
            const int row = i * 8 + w;
            float4 v0 = *reinterpret_cast<const float4*>(&sbuf[row][4 * lane]);
            float4 v1 = *reinterpret_cast<const float4*>(&sbuf[row][256 + 4 * lane]);
            float* dst = arow + (size_t)row * NN + m * 512 + 4 * lane;
            *reinterpret_cast<float4*>(dst)       = v0;
            *reinterpret_cast<float4*>(dst + 256) = v1;
        }
        lds_barrier();   // protect sbuf WAR before next stage
    }
}

// ---------------------------------------------------------------------------
// K4: PV (gamma-guarded; grid-stride)
// ---------------------------------------------------------------------------
__global__ __launch_bounds__(256) void pv_kernel(
    const float* __restrict__ att, const float* __restrict__ Vt,
    const float* __restrict__ gamma, float* __restrict__ Pt)
{
    if (gamma[0] == 0.f) return;
    const size_t total = (size_t)BB * NN * CC;
    for (size_t idx = (size_t)blockIdx.x * 256 + threadIdx.x; idx < total;
         idx += (size_t)1024 * 256) {
        const int c = (int)(idx % CC);
        const size_t bn = idx / CC;
        const int i = (int)(bn % NN);
        const int b = (int)(bn / NN);

        const float* arow = att + ((size_t)b * NN + i) * NN;
        const float* vcol = Vt + (size_t)b * NN * CC + c;
        float acc = 0.f;
        for (int j = 0; j < NN; ++j) acc += arow[j] * vcol[(size_t)j * CC];
        Pt[idx] = acc;
    }
}

// ---------------------------------------------------------------------------
// K5: out = gamma * PV + x (gamma!=0 only; grid-stride)
// ---------------------------------------------------------------------------
__global__ __launch_bounds__(256) void out_kernel(
    const float* __restrict__ x, const float* __restrict__ Pt,
    const float* __restrict__ gamma, float* __restrict__ out)
{
    const float g = gamma[0];
    if (g == 0.f) return;
    const size_t total4 = (size_t)BB * CC * NN / 4;
    for (size_t t = (size_t)blockIdx.x * 256 + threadIdx.x; t < total4;
         t += (size_t)512 * 256) {
        const size_t i4 = t * 4;
        float4 v = *reinterpret_cast<const float4*>(x + i4);
        #pragma unroll
        for (int e = 0; e < 4; ++e) {
            const size_t idx = i4 + e;
            const int n = (int)(idx % NN);
            const size_t bc = idx / NN;
            const int c = (int)(bc % CC);
            const int bb = (int)(bc / CC);
            (&v.x)[e] += g * Pt[((size_t)bb * NN + n) * CC + c];
        }
        *reinterpret_cast<float4*>(out + i4) = v;
    }
}

extern "C" void kernel_launch(void* const* d_in, const int* in_sizes, int n_in,
                              void* d_out, int out_size, void* d_ws, size_t ws_size,
                              hipStream_t stream)
{
    const float* x     = (const float*)d_in[0];
    const float* wq    = (const float*)d_in[1];
    const float* bq    = (const float*)d_in[2];
    const float* wk    = (const float*)d_in[3];
    const float* bk    = (const float*)d_in[4];
    const float* wv    = (const float*)d_in[5];
    const float* bv    = (const float*)d_in[6];
    const float* gamma = (const float*)d_in[7];

    float* out = (float*)d_out;                    // [B,C,W,H]
    float* att = out + (size_t)BB * CC * NN;       // [B,N,N]

    unsigned short* Qtb = (unsigned short*)d_ws;             // B*N*CQ bf16 (1 MB)
    unsigned short* Ktb = Qtb + (size_t)BB * NN * CQ;        // 1 MB
    float* Vt = (float*)(Ktb + (size_t)BB * NN * CQ);        // B*N*C f32
    float* Pt = Vt + (size_t)BB * NN * CC;

    qk_proj_kernel<<<dim3(NN / 128, 8, BB), 128, 0, stream>>>(x, wq, bq, wk, bk, Qtb, Ktb, out);
    v_proj_kernel<<<dim3(256), 256, 0, stream>>>(x, wv, bv, gamma, Vt);
    attn_kernel<<<dim3(512), 512, 0, stream>>>(Qtb, Ktb, att);
    pv_kernel<<<dim3(1024), 256, 0, stream>>>(att, Vt, gamma, Pt);
    out_kernel<<<dim3(512), 256, 0, stream>>>(x, Pt, gamma, out);
}

// Round 18
// 106.846 us; speedup vs baseline: 1.0442x; 1.0442x over previous
//
#include <hip/hip_runtime.h>

#define BB 4
#define CC 256
#define CQ 32
#define NN 4096   // 64*64

typedef __attribute__((ext_vector_type(8))) short bf16x8;
typedef __attribute__((ext_vector_type(16))) float f32x16;

__device__ __forceinline__ unsigned short f2bf(float f) {
    unsigned int u = __float_as_uint(f);
    unsigned int r = (u + 0x7fffu + ((u >> 16) & 1u)) >> 16;
    return (unsigned short)r;
}

// ---------------------------------------------------------------------------
// K1: Q/K projections -> transposed bf16 buffers [b][n][cq].  (R16-identical)
// ---------------------------------------------------------------------------
__global__ __launch_bounds__(128) void qk_proj_kernel(
    const float* __restrict__ x,
    const float* __restrict__ wq, const float* __restrict__ bq,
    const float* __restrict__ wk, const float* __restrict__ bk,
    unsigned short* __restrict__ Qtb, unsigned short* __restrict__ Ktb,
    float* __restrict__ out)
{
    const int n   = blockIdx.x * 128 + threadIdx.x;
    const int grp = blockIdx.y;
    const int b   = blockIdx.z;
    const bool isQ = (grp < 4);
    const bool doCopy = (grp == 0);
    const int o0 = (grp & 3) * 8;

    const float* w    = isQ ? wq : wk;
    const float* bias = isQ ? bq : bk;

    float acc[8];
    #pragma unroll
    for (int u = 0; u < 8; ++u) acc[u] = bias[o0 + u];

    const float* xp = x + (size_t)b * CC * NN + n;
    float* op = out + (size_t)b * CC * NN + n;
    const float* wp = w + (size_t)o0 * CC;
    #pragma unroll 8
    for (int c = 0; c < CC; ++c) {
        float xv = xp[(size_t)c * NN];
        if (doCopy) op[(size_t)c * NN] = xv;
        #pragma unroll
        for (int u = 0; u < 8; ++u) acc[u] += wp[u * CC + c] * xv;
    }

    unsigned int pk[4];
    #pragma unroll
    for (int j = 0; j < 4; ++j)
        pk[j] = (unsigned int)f2bf(acc[2 * j]) | ((unsigned int)f2bf(acc[2 * j + 1]) << 16);

    unsigned short* dst = (isQ ? Qtb : Ktb) + ((size_t)b * NN + n) * CQ;
    *reinterpret_cast<uint4*>(dst + o0) = make_uint4(pk[0], pk[1], pk[2], pk[3]);
}

// ---------------------------------------------------------------------------
// K2: V projection (gamma-guarded; grid-stride)
// ---------------------------------------------------------------------------
__global__ __launch_bounds__(256) void v_proj_kernel(
    const float* __restrict__ x,
    const float* __restrict__ wv, const float* __restrict__ bv,
    const float* __restrict__ gamma,
    float* __restrict__ Vt)
{
    if (gamma[0] == 0.f) return;
    for (int task = blockIdx.x; task < 2048; task += 256) {
        const int n  = (task & 15) * 256 + threadIdx.x;
        const int c0 = ((task >> 4) & 31) * 8;
        const int b  = task >> 9;

        float acc[8];
        #pragma unroll
        for (int u = 0; u < 8; ++u) acc[u] = 0.f;

        const float* xp = x + (size_t)b * CC * NN + n;
        #pragma unroll 4
        for (int c = 0; c < CC; ++c) {
            float xv = xp[(size_t)c * NN];
            #pragma unroll
            for (int u = 0; u < 8; ++u) acc[u] += wv[(size_t)(c0 + u) * CC + c] * xv;
        }
        #pragma unroll
        for (int u = 0; u < 8; ++u)
            Vt[((size_t)b * NN + n) * CC + c0 + u] = acc[u] + bv[c0 + u];
    }
}

// ---------------------------------------------------------------------------
// K3: 2-pass MFMA energy + softmax. Pass 1 + XCD swizzle: R16-identical.
// Pass 2: R16 structure, ONE change — transpose tile widened to TWO u-tiles
// (tr[8][64][33], wave-private, no barriers) drained every second u with
// float2 stores: half-wave = 256B contiguous per row (was 128B), store
// instruction count halved. LDS op counts unchanged, conflict-free.
// ---------------------------------------------------------------------------
__global__ __launch_bounds__(512, 4) void attn_kernel(
    const unsigned short* __restrict__ Qtb,
    const unsigned short* __restrict__ Ktb,
    float* __restrict__ att)
{
    __shared__ float red_s[8][32];
    __shared__ float rowls[32];
    __shared__ float tr[8][64][33];

    const int tid  = threadIdx.x;
    const int w    = tid >> 6;
    const int lane = tid & 63;
    const int l31  = lane & 31;
    const int h    = lane >> 5;

    // XCD-aware bijective swizzle (R16): XCD (flat&7) -> contiguous 64 tiles
    const int flat = blockIdx.x;
    const int orig = (flat >> 3) + ((flat & 7) << 6);
    const int b    = orig >> 7;
    const int i0   = (orig & 127) * 32;

    // Q-frags (B operand): col i = i0+l31; k-chunks h and h+2 (8 cq each)
    const unsigned short* qb = Qtb + ((size_t)b * NN + i0 + l31) * CQ;
    const bf16x8 a0 = *reinterpret_cast<const bf16x8*>(qb + h * 8);
    const bf16x8 a1 = *reinterpret_cast<const bf16x8*>(qb + (h + 2) * 8);

    // K-frags (A operand): row j = w*512 + u*32 + l31; same k-chunks
    const unsigned short* kf = Ktb + ((size_t)b * NN + w * 512 + l31) * CQ;

    // ---------------- pass 1: per-lane row-sum of exp (R16-identical) ------
    float s = 0.f;
    {
        bf16x8 nb0 = *reinterpret_cast<const bf16x8*>(kf + h * 8);
        bf16x8 nb1 = *reinterpret_cast<const bf16x8*>(kf + (h + 2) * 8);
        #pragma unroll
        for (int u = 0; u < 16; ++u) {
            bf16x8 b0 = nb0, b1 = nb1;
            if (u < 15) {
                const unsigned short* kp = kf + (size_t)(u + 1) * 32 * CQ;
                nb0 = *reinterpret_cast<const bf16x8*>(kp + h * 8);
                nb1 = *reinterpret_cast<const bf16x8*>(kp + (h + 2) * 8);
            }
            f32x16 acc{};
            acc = __builtin_amdgcn_mfma_f32_32x32x16_bf16(b0, a0, acc, 0, 0, 0);
            acc = __builtin_amdgcn_mfma_f32_32x32x16_bf16(b1, a1, acc, 0, 0, 0);
            float p0 = 0.f, p1 = 0.f;
            #pragma unroll
            for (int q = 0; q < 16; q += 2) {
                p0 += __expf(acc[q]);
                p1 += __expf(acc[q + 1]);
            }
            s += p0 + p1;
        }
    }
    s += __shfl_xor(s, 32, 64);
    if (h == 0) red_s[w][l31] = s;
    __syncthreads();
    if (tid < 32) {
        float t = red_s[0][tid];
        #pragma unroll
        for (int ww = 1; ww < 8; ++ww) t += red_s[ww][tid];
        rowls[tid] = -__logf(t);
    }
    __syncthreads();
    const float lis = rowls[l31];

    // ------- pass 2: recompute (prefetched), 2-u-tile transpose, f2 store --
    float* abase = att + ((size_t)b * NN + i0) * NN + w * 512;
    {
        bf16x8 nb0 = *reinterpret_cast<const bf16x8*>(kf + h * 8);
        bf16x8 nb1 = *reinterpret_cast<const bf16x8*>(kf + (h + 2) * 8);
        #pragma unroll
        for (int u = 0; u < 16; ++u) {
            bf16x8 b0 = nb0, b1 = nb1;
            if (u < 15) {
                const unsigned short* kp = kf + (size_t)(u + 1) * 32 * CQ;
                nb0 = *reinterpret_cast<const bf16x8*>(kp + h * 8);
                nb1 = *reinterpret_cast<const bf16x8*>(kp + (h + 2) * 8);
            }
            f32x16 acc{};
            acc = __builtin_amdgcn_mfma_f32_32x32x16_bf16(b0, a0, acc, 0, 0, 0);
            acc = __builtin_amdgcn_mfma_f32_32x32x16_bf16(b1, a1, acc, 0, 0, 0);
            // write transposed into the (u&1) half of the wide tile:
            // lane holds q-row l31, macro-col (u&1)*32 + kc
            #pragma unroll
            for (int q = 0; q < 16; ++q) {
                const int kc = ((u & 1) << 5) + (q & 3) + 8 * (q >> 2) + 4 * h;
                tr[w][kc][l31] = __expf(acc[q] + lis);
            }
            if (u & 1) {
                // drain both u-tiles: float2 per row -> 256B/half-wave chunk
                const int mcol = (u >> 1) * 64;
                #pragma unroll
                for (int k = 0; k < 16; ++k) {
                    const int row = 2 * k + h;
                    float2 v;
                    v.x = tr[w][2 * l31][row];
                    v.y = tr[w][2 * l31 + 1][row];
                    *reinterpret_cast<float2*>(
                        abase + (size_t)row * NN + mcol + 2 * l31) = v;
                }
            }
        }
    }
}

// ---------------------------------------------------------------------------
// K4: PV (gamma-guarded; grid-stride)
// ---------------------------------------------------------------------------
__global__ __launch_bounds__(256) void pv_kernel(
    const float* __restrict__ att, const float* __restrict__ Vt,
    const float* __restrict__ gamma, float* __restrict__ Pt)
{
    if (gamma[0] == 0.f) return;
    const size_t total = (size_t)BB * NN * CC;
    for (size_t idx = (size_t)blockIdx.x * 256 + threadIdx.x; idx < total;
         idx += (size_t)1024 * 256) {
        const int c = (int)(idx % CC);
        const size_t bn = idx / CC;
        const int i = (int)(bn % NN);
        const int b = (int)(bn / NN);

        const float* arow = att + ((size_t)b * NN + i) * NN;
        const float* vcol = Vt + (size_t)b * NN * CC + c;
        float acc = 0.f;
        for (int j = 0; j < NN; ++j) acc += arow[j] * vcol[(size_t)j * CC];
        Pt[idx] = acc;
    }
}

// ---------------------------------------------------------------------------
// K5: out = gamma * PV + x (gamma!=0 only; grid-stride)
// ---------------------------------------------------------------------------
__global__ __launch_bounds__(256) void out_kernel(
    const float* __restrict__ x, const float* __restrict__ Pt,
    const float* __restrict__ gamma, float* __restrict__ out)
{
    const float g = gamma[0];
    if (g == 0.f) return;
    const size_t total4 = (size_t)BB * CC * NN / 4;
    for (size_t t = (size_t)blockIdx.x * 256 + threadIdx.x; t < total4;
         t += (size_t)512 * 256) {
        const size_t i4 = t * 4;
        float4 v = *reinterpret_cast<const float4*>(x + i4);
        #pragma unroll
        for (int e = 0; e < 4; ++e) {
            const size_t idx = i4 + e;
            const int n = (int)(idx % NN);
            const size_t bc = idx / NN;
            const int c = (int)(bc % CC);
            const int bb = (int)(bc / CC);
            (&v.x)[e] += g * Pt[((size_t)bb * NN + n) * CC + c];
        }
        *reinterpret_cast<float4*>(out + i4) = v;
    }
}

extern "C" void kernel_launch(void* const* d_in, const int* in_sizes, int n_in,
                              void* d_out, int out_size, void* d_ws, size_t ws_size,
                              hipStream_t stream)
{
    const float* x     = (const float*)d_in[0];
    const float* wq    = (const float*)d_in[1];
    const float* bq    = (const float*)d_in[2];
    const float* wk    = (const float*)d_in[3];
    const float* bk    = (const float*)d_in[4];
    const float* wv    = (const float*)d_in[5];
    const float* bv    = (const float*)d_in[6];
    const float* gamma = (const float*)d_in[7];

    float* out = (float*)d_out;                    // [B,C,W,H]
    float* att = out + (size_t)BB * CC * NN;       // [B,N,N]

    unsigned short* Qtb = (unsigned short*)d_ws;             // B*N*CQ bf16 (1 MB)
    unsigned short* Ktb = Qtb + (size_t)BB * NN * CQ;        // 1 MB
    float* Vt = (float*)(Ktb + (size_t)BB * NN * CQ);        // B*N*C f32
    float* Pt = Vt + (size_t)BB * NN * CC;

    qk_proj_kernel<<<dim3(NN / 128, 8, BB), 128, 0, stream>>>(x, wq, bq, wk, bk, Qtb, Ktb, out);
    v_proj_kernel<<<dim3(256), 256, 0, stream>>>(x, wv, bv, gamma, Vt);
    attn_kernel<<<dim3(512), 512, 0, stream>>>(Qtb, Ktb, att);
    pv_kernel<<<dim3(1024), 256, 0, stream>>>(att, Vt, gamma, Pt);
    out_kernel<<<dim3(512), 256, 0, stream>>>(x, Pt, gamma, out);
}

// Round 19
// 104.661 us; speedup vs baseline: 1.0660x; 1.0209x over previous
//
#include <hip/hip_runtime.h>

#define BB 4
#define CC 256
#define CQ 32
#define NN 4096   // 64*64

typedef __attribute__((ext_vector_type(8))) short bf16x8;
typedef __attribute__((ext_vector_type(16))) float f32x16;

__device__ __forceinline__ unsigned short f2bf(float f) {
    unsigned int u = __float_as_uint(f);
    unsigned int r = (u + 0x7fffu + ((u >> 16) & 1u)) >> 16;
    return (unsigned short)r;
}

// ---------------------------------------------------------------------------
// K1: Q/K projections -> transposed bf16 buffers [b][n][cq].  (R16-identical)
// grid (NN/128, 8, BB), block 128: grp 0-3 = Q rows grp*8..+8,
// grp 4-7 = K rows (grp-4)*8..+8. grp 0 also streams out = x.
// ---------------------------------------------------------------------------
__global__ __launch_bounds__(128) void qk_proj_kernel(
    const float* __restrict__ x,
    const float* __restrict__ wq, const float* __restrict__ bq,
    const float* __restrict__ wk, const float* __restrict__ bk,
    unsigned short* __restrict__ Qtb, unsigned short* __restrict__ Ktb,
    float* __restrict__ out)
{
    const int n   = blockIdx.x * 128 + threadIdx.x;
    const int grp = blockIdx.y;
    const int b   = blockIdx.z;
    const bool isQ = (grp < 4);
    const bool doCopy = (grp == 0);
    const int o0 = (grp & 3) * 8;

    const float* w    = isQ ? wq : wk;
    const float* bias = isQ ? bq : bk;

    float acc[8];
    #pragma unroll
    for (int u = 0; u < 8; ++u) acc[u] = bias[o0 + u];

    const float* xp = x + (size_t)b * CC * NN + n;
    float* op = out + (size_t)b * CC * NN + n;
    const float* wp = w + (size_t)o0 * CC;
    #pragma unroll 8
    for (int c = 0; c < CC; ++c) {
        float xv = xp[(size_t)c * NN];
        if (doCopy) op[(size_t)c * NN] = xv;
        #pragma unroll
        for (int u = 0; u < 8; ++u) acc[u] += wp[u * CC + c] * xv;
    }

    unsigned int pk[4];
    #pragma unroll
    for (int j = 0; j < 4; ++j)
        pk[j] = (unsigned int)f2bf(acc[2 * j]) | ((unsigned int)f2bf(acc[2 * j + 1]) << 16);

    unsigned short* dst = (isQ ? Qtb : Ktb) + ((size_t)b * NN + n) * CQ;
    *reinterpret_cast<uint4*>(dst + o0) = make_uint4(pk[0], pk[1], pk[2], pk[3]);
}

// ---------------------------------------------------------------------------
// K2: V projection -> Vt[b][n][c]  (gamma-guarded; grid-stride, small grid)
// ---------------------------------------------------------------------------
__global__ __launch_bounds__(256) void v_proj_kernel(
    const float* __restrict__ x,
    const float* __restrict__ wv, const float* __restrict__ bv,
    const float* __restrict__ gamma,
    float* __restrict__ Vt)
{
    if (gamma[0] == 0.f) return;
    for (int task = blockIdx.x; task < 2048; task += 256) {
        const int n  = (task & 15) * 256 + threadIdx.x;
        const int c0 = ((task >> 4) & 31) * 8;
        const int b  = task >> 9;

        float acc[8];
        #pragma unroll
        for (int u = 0; u < 8; ++u) acc[u] = 0.f;

        const float* xp = x + (size_t)b * CC * NN + n;
        #pragma unroll 4
        for (int c = 0; c < CC; ++c) {
            float xv = xp[(size_t)c * NN];
            #pragma unroll
            for (int u = 0; u < 8; ++u) acc[u] += wv[(size_t)(c0 + u) * CC + c] * xv;
        }
        #pragma unroll
        for (int u = 0; u < 8; ++u)
            Vt[((size_t)b * NN + n) * CC + c0 + u] = acc[u] + bv[c0 + u];
    }
}

// ---------------------------------------------------------------------------
// K3: 2-pass MFMA energy + softmax (R16-identical — empirical optimum).
// XCD-aware bijective swizzle; swapped operands mfma(K,Q) -> lane-local row
// softmax; pass-2 wave-private single-buffer LDS transpose (tr[8][32][33],
// 33.8 KB) -> coalesced scalar stores (half-wave = 128B line), barrier-free.
// ---------------------------------------------------------------------------
__global__ __launch_bounds__(512, 4) void attn_kernel(
    const unsigned short* __restrict__ Qtb,
    const unsigned short* __restrict__ Ktb,
    float* __restrict__ att)
{
    __shared__ float red_s[8][32];
    __shared__ float rowls[32];
    __shared__ float tr[8][32][33];

    const int tid  = threadIdx.x;
    const int w    = tid >> 6;
    const int lane = tid & 63;
    const int l31  = lane & 31;
    const int h    = lane >> 5;

    // XCD-aware bijective swizzle: XCD (flat&7) -> contiguous 64 tiles
    const int flat = blockIdx.x;
    const int orig = (flat >> 3) + ((flat & 7) << 6);
    const int b    = orig >> 7;
    const int i0   = (orig & 127) * 32;

    // Q-frags (B operand): col i = i0+l31; k-chunks h and h+2 (8 cq each)
    const unsigned short* qb = Qtb + ((size_t)b * NN + i0 + l31) * CQ;
    const bf16x8 a0 = *reinterpret_cast<const bf16x8*>(qb + h * 8);
    const bf16x8 a1 = *reinterpret_cast<const bf16x8*>(qb + (h + 2) * 8);

    // K-frags (A operand): row j = w*512 + u*32 + l31; same k-chunks
    const unsigned short* kf = Ktb + ((size_t)b * NN + w * 512 + l31) * CQ;

    // ---------------- pass 1: per-lane row-sum of exp (prefetched) ---------
    float s = 0.f;
    {
        bf16x8 nb0 = *reinterpret_cast<const bf16x8*>(kf + h * 8);
        bf16x8 nb1 = *reinterpret_cast<const bf16x8*>(kf + (h + 2) * 8);
        #pragma unroll
        for (int u = 0; u < 16; ++u) {
            bf16x8 b0 = nb0, b1 = nb1;
            if (u < 15) {
                const unsigned short* kp = kf + (size_t)(u + 1) * 32 * CQ;
                nb0 = *reinterpret_cast<const bf16x8*>(kp + h * 8);
                nb1 = *reinterpret_cast<const bf16x8*>(kp + (h + 2) * 8);
            }
            f32x16 acc{};
            acc = __builtin_amdgcn_mfma_f32_32x32x16_bf16(b0, a0, acc, 0, 0, 0);
            acc = __builtin_amdgcn_mfma_f32_32x32x16_bf16(b1, a1, acc, 0, 0, 0);
            float p0 = 0.f, p1 = 0.f;
            #pragma unroll
            for (int q = 0; q < 16; q += 2) {
                p0 += __expf(acc[q]);
                p1 += __expf(acc[q + 1]);
            }
            s += p0 + p1;
        }
    }
    s += __shfl_xor(s, 32, 64);
    if (h == 0) red_s[w][l31] = s;
    __syncthreads();
    if (tid < 32) {
        float t = red_s[0][tid];
        #pragma unroll
        for (int ww = 1; ww < 8; ++ww) t += red_s[ww][tid];
        rowls[tid] = -__logf(t);
    }
    __syncthreads();
    const float lis = rowls[l31];

    // ------- pass 2: recompute (prefetched), LDS transpose, store ----------
    float* abase = att + ((size_t)b * NN + i0) * NN + w * 512;
    {
        bf16x8 nb0 = *reinterpret_cast<const bf16x8*>(kf + h * 8);
        bf16x8 nb1 = *reinterpret_cast<const bf16x8*>(kf + (h + 2) * 8);
        #pragma unroll
        for (int u = 0; u < 16; ++u) {
            bf16x8 b0 = nb0, b1 = nb1;
            if (u < 15) {
                const unsigned short* kp = kf + (size_t)(u + 1) * 32 * CQ;
                nb0 = *reinterpret_cast<const bf16x8*>(kp + h * 8);
                nb1 = *reinterpret_cast<const bf16x8*>(kp + (h + 2) * 8);
            }
            f32x16 acc{};
            acc = __builtin_amdgcn_mfma_f32_32x32x16_bf16(b0, a0, acc, 0, 0, 0);
            acc = __builtin_amdgcn_mfma_f32_32x32x16_bf16(b1, a1, acc, 0, 0, 0);
            // write transposed: lane holds query-row l31, k-col (q&3)+8*(q>>2)+4h
            #pragma unroll
            for (int q = 0; q < 16; ++q) {
                const int kc = (q & 3) + 8 * (q >> 2) + 4 * h;
                tr[w][kc][l31] = __expf(acc[q] + lis);
            }
            // read back row-major: lane -> (row 2k+h, col l31); half-wave = line
            #pragma unroll
            for (int k = 0; k < 16; ++k) {
                const int row = 2 * k + h;
                abase[(size_t)row * NN + u * 32 + l31] = tr[w][l31][row];
            }
        }
    }
}

// ---------------------------------------------------------------------------
// K4: fused PV + output: out[b,c,n] = x[b,c,n] + g * sum_j att[b,n,j]*Vt[b,j,c]
// (gamma-guarded; grid-stride; replaces the former pv + out pair — one fewer
// dispatch, no Pt round-trip)
// ---------------------------------------------------------------------------
__global__ __launch_bounds__(256) void pv_out_kernel(
    const float* __restrict__ x, const float* __restrict__ att,
    const float* __restrict__ Vt, const float* __restrict__ gamma,
    float* __restrict__ out)
{
    const float g = gamma[0];
    if (g == 0.f) return;
    const size_t total = (size_t)BB * CC * NN;
    for (size_t idx = (size_t)blockIdx.x * 256 + threadIdx.x; idx < total;
         idx += (size_t)1024 * 256) {
        const int n = (int)(idx % NN);
        const size_t bc = idx / NN;
        const int c = (int)(bc % CC);
        const int b = (int)(bc / CC);

        const float* arow = att + ((size_t)b * NN + n) * NN;
        const float* vcol = Vt + (size_t)b * NN * CC + c;
        float acc = 0.f;
        for (int j = 0; j < NN; ++j) acc += arow[j] * vcol[(size_t)j * CC];
        out[idx] = x[idx] + g * acc;
    }
}

extern "C" void kernel_launch(void* const* d_in, const int* in_sizes, int n_in,
                              void* d_out, int out_size, void* d_ws, size_t ws_size,
                              hipStream_t stream)
{
    const float* x     = (const float*)d_in[0];
    const float* wq    = (const float*)d_in[1];
    const float* bq    = (const float*)d_in[2];
    const float* wk    = (const float*)d_in[3];
    const float* bk    = (const float*)d_in[4];
    const float* wv    = (const float*)d_in[5];
    const float* bv    = (const float*)d_in[6];
    const float* gamma = (const float*)d_in[7];

    float* out = (float*)d_out;                    // [B,C,W,H]
    float* att = out + (size_t)BB * CC * NN;       // [B,N,N]

    unsigned short* Qtb = (unsigned short*)d_ws;             // B*N*CQ bf16 (1 MB)
    unsigned short* Ktb = Qtb + (size_t)BB * NN * CQ;        // 1 MB
    float* Vt = (float*)(Ktb + (size_t)BB * NN * CQ);        // B*N*C f32

    qk_proj_kernel<<<dim3(NN / 128, 8, BB), 128, 0, stream>>>(x, wq, bq, wk, bk, Qtb, Ktb, out);
    v_proj_kernel<<<dim3(256), 256, 0, stream>>>(x, wv, bv, gamma, Vt);
    attn_kernel<<<dim3(512), 512, 0, stream>>>(Qtb, Ktb, att);
    pv_out_kernel<<<dim3(1024), 256, 0, stream>>>(x, att, Vt, gamma, out);
}